// Round 6
// baseline (211.366 us; speedup 1.0000x reference)
//
#include <hip/hip_runtime.h>
#include <hip/hip_bf16.h>

#define N_NODES 10000
#define KNEI    30
#define DIM     128
#define EDGES   (N_NODES * KNEI)

typedef __attribute__((ext_vector_type(4))) float  f32x4;
typedef __attribute__((ext_vector_type(8))) __bf16 bf16x8;
typedef __attribute__((ext_vector_type(4))) __bf16 bf16x4;

// packed bf16 weight offsets in d_ws (element units)
// CW1: K=256, N=256 combined [att_w1(e|hj part) | node_w1]   tiles: kt*16+nt
// CW2: K=128, N=256 combined [att_w2 | node_w2]              tiles: kt*16+nt
// NW3/HI/TH: K=128, N=128                                    tiles: kt*8+nt
#define OFF_CW1 0
#define OFF_CW2 65536
#define OFF_NW3 98304
#define OFF_HI  114688
#define OFF_TH  131072
#define TOT_TILES 288
#define YHI_BYTE_OFF (300 * 1024)   // f32 yhi[N][128] after weights

// Pack all weights (f32) into MFMA A-fragment order, bf16, one launch.
// Within a 512-elem tile: lane holds n = nt*16+(lane&15), k = kt*32+(lane>>4)*8+i.
__global__ __launch_bounds__(256) void repack_all(
    const float* __restrict__ aw1, const float* __restrict__ aw2,
    const float* __restrict__ nw1, const float* __restrict__ nw2,
    const float* __restrict__ nw3, const float* __restrict__ thw,
    __bf16* __restrict__ dst) {
    int t = blockIdx.x * 256 + threadIdx.x;
    if (t >= TOT_TILES * 512) return;
    int tile = t >> 9;
    int i    = t & 7;
    int lane = (t >> 3) & 63;
    int krow = ((lane >> 4) << 3) + i;   // 0..31
    int ncol = lane & 15;
    float v;
    if (tile < 128) {                    // CW1
        int kt = tile >> 4, nt = tile & 15;
        int k = kt * 32 + krow, n = nt * 16 + ncol;
        v = (n < 128) ? aw1[(128 + k) * 128 + n] : nw1[k * 128 + (n - 128)];
    } else if (tile < 192) {             // CW2
        int lt = tile - 128;
        int kt = lt >> 4, nt = lt & 15;
        int k = kt * 32 + krow, n = nt * 16 + ncol;
        v = (n < 128) ? aw2[k * 128 + n] : nw2[k * 128 + (n - 128)];
    } else {                             // NW3 / HI / TH (32 tiles each)
        int lt = tile & 31;
        int kt = lt >> 3, nt = lt & 7;
        int k = kt * 32 + krow, n = nt * 16 + ncol;
        const float* s = (tile < 224) ? nw3 : (tile < 256) ? aw1 : thw;
        v = s[k * 128 + n];
    }
    dst[t] = (__bf16)v;
}

// fast gelu (tanh form; abs err ~2e-4, << bf16 noise)
__device__ __forceinline__ float gelu_f(float x) {
    float u = 0.7978845608f * (x + 0.044715f * x * x * x);
    float t = 1.f - 2.f / (__expf(2.f * u) + 1.f);
    return 0.5f * x * (1.f + t);
}

__device__ __forceinline__ bf16x4 cvt4(float4 v) {
    bf16x4 r;
    r[0] = (__bf16)v.x; r[1] = (__bf16)v.y; r[2] = (__bf16)v.z; r[3] = (__bf16)v.w;
    return r;
}

// ---- generic 128->128 row GEMM (64 rows/block, 8 waves): out = in @ Wfrag (+bias) ----
__global__ __launch_bounds__(512) void mm128(const float* __restrict__ in,
                                             float* __restrict__ outp,
                                             const __bf16* __restrict__ wfrag,
                                             const float* __restrict__ bias) {
    __shared__ __bf16 sP[64 * 136];
    const int tid  = threadIdx.x;
    const int wv   = tid >> 6;
    const int lane = tid & 63;
    const int mrow = lane & 15;
    const int kgrp = lane >> 4;
    const int base = blockIdx.x * 64;

#pragma unroll
    for (int c = 0; c < 4; ++c) {
        int idx = c * 512 + tid;
        int m  = idx >> 5;
        int jv = idx & 31;
        int row = base + m;
        float4 v = make_float4(0.f, 0.f, 0.f, 0.f);
        if (row < N_NODES) v = *reinterpret_cast<const float4*>(in + (long)row * DIM + jv * 4);
        *reinterpret_cast<bf16x4*>(&sP[m * 136 + jv * 4]) = cvt4(v);
    }
    __syncthreads();

    f32x4 acc[4];
#pragma unroll
    for (int mf = 0; mf < 4; ++mf) acc[mf] = (f32x4){0.f, 0.f, 0.f, 0.f};
#pragma unroll
    for (int kt = 0; kt < 4; ++kt) {
        bf16x8 a = *reinterpret_cast<const bf16x8*>(wfrag + ((kt * 8 + wv) * 64 + lane) * 8);
        const int kb = kt * 32 + kgrp * 8;
#pragma unroll
        for (int mf = 0; mf < 4; ++mf) {
            bf16x8 b = *reinterpret_cast<const bf16x8*>(sP + (mf * 16 + mrow) * 136 + kb);
            acc[mf] = __builtin_amdgcn_mfma_f32_16x16x32_bf16(a, b, acc[mf], 0, 0, 0);
        }
    }
    const int nb = wv * 16 + kgrp * 4;
    float b0 = 0.f, b1 = 0.f, b2 = 0.f, b3 = 0.f;
    if (bias) { b0 = bias[nb]; b1 = bias[nb + 1]; b2 = bias[nb + 2]; b3 = bias[nb + 3]; }
#pragma unroll
    for (int mf = 0; mf < 4; ++mf) {
        int row = base + mf * 16 + mrow;
        if (row < N_NODES) {
            float4 o = make_float4(acc[mf][0] + b0, acc[mf][1] + b1,
                                   acc[mf][2] + b2, acc[mf][3] + b3);
            *reinterpret_cast<float4*>(outp + (long)row * DIM + nb) = o;
        }
    }
}

// ---- fused kernel: one block = 1 node (30 edges padded to 32 rows), 4 waves ----
// Layer-1 and layer-2 of both MLPs run as COMBINED 256-output GEMMs (shared or
// wave-split inputs). LDS: union buffer U = S[32][264] then Y1|Y2[32][136].
__global__ __launch_bounds__(256, 6) void gnn_fused(
    const float* __restrict__ h, const float* __restrict__ e, const int* __restrict__ eidx,
    const float* __restrict__ yhi,
    const float* __restrict__ ab2, const float* __restrict__ aw3, const float* __restrict__ ab3,
    const float* __restrict__ nb1, const float* __restrict__ nb2, const float* __restrict__ nb3,
    const __bf16* __restrict__ wp, float* __restrict__ pre_out) {

    __shared__ __bf16 U[8704];          // S: stride 264 (8448 used) ; later Y1@0, Y2@4352 (stride 136)
    __shared__ float  sLP[2][32][4];    // logit partials (wave-half 0/1)
    __shared__ float  sW[32][4];        // softmax weights (rows 30/31 = 0)

    const int tid  = threadIdx.x;
    const int wv   = tid >> 6;
    const int lane = tid & 63;
    const int mrow = lane & 15;
    const int kg   = lane >> 4;
    const int node = blockIdx.x;
    const long ebase = (long)node * KNEI;

    // ---- P0: stage e|hj (f32 -> bf16), pad rows 30/31 = 0 ----
#pragma unroll
    for (int c = 0; c < 4; ++c) {
        int idx = c * 256 + tid;
        int m  = idx >> 5;   // row 0..31
        int jv = idx & 31;   // float4 col
        float4 ev = make_float4(0.f, 0.f, 0.f, 0.f), hjv = ev;
        if (m < KNEI) {
            long ge = ebase + m;
            ev  = *reinterpret_cast<const float4*>(e + ge * DIM + jv * 4);
            int dstn = eidx[EDGES + ge];
            hjv = *reinterpret_cast<const float4*>(h + (long)dstn * DIM + jv * 4);
        }
        *reinterpret_cast<bf16x4*>(&U[m * 264 + jv * 4])       = cvt4(ev);
        *reinterpret_cast<bf16x4*>(&U[m * 264 + 128 + jv * 4]) = cvt4(hjv);
    }
    __syncthreads();   // b0

    f32x4 acc[4][2];
#pragma unroll
    for (int j = 0; j < 4; ++j) { acc[j][0] = (f32x4){0.f,0.f,0.f,0.f}; acc[j][1] = (f32x4){0.f,0.f,0.f,0.f}; }

    // ---- P1: combined layer-1 (K=256): [att1 | node1] over shared [e|hj] ----
    {
        const __bf16* b0p = U + mrow * 264;
        const __bf16* b1p = U + (16 + mrow) * 264;
#pragma unroll
        for (int kt = 0; kt < 8; ++kt) {
            const int kb = kt * 32 + kg * 8;
            bf16x8 b0 = *reinterpret_cast<const bf16x8*>(b0p + kb);
            bf16x8 b1 = *reinterpret_cast<const bf16x8*>(b1p + kb);
#pragma unroll
            for (int j = 0; j < 4; ++j) {
                bf16x8 a = *reinterpret_cast<const bf16x8*>(wp + OFF_CW1 + (size_t)((kt * 16 + wv * 4 + j) * 64 + lane) * 8);
                acc[j][0] = __builtin_amdgcn_mfma_f32_16x16x32_bf16(a, b0, acc[j][0], 0, 0, 0);
                acc[j][1] = __builtin_amdgcn_mfma_f32_16x16x32_bf16(a, b1, acc[j][1], 0, 0, 0);
            }
        }
    }
    __syncthreads();   // b1a: all reads of S done; U re-carved as Y1|Y2

    // ---- epilogue 1: waves 0/1 -> relu(acc + yhi) -> Y1 ; waves 2/3 -> gelu(acc + nb1) -> Y2 ----
    {
        const bool isatt = (wv < 2);
        __bf16* Y = U + (isatt ? 0 : 4352);
        const float* yrow = yhi + (long)node * DIM;
#pragma unroll
        for (int j = 0; j < 4; ++j) {
            const int f = (wv & 1) * 64 + j * 16 + kg * 4;
            float b0, b1, b2, b3;
            if (isatt) { b0 = yrow[f]; b1 = yrow[f+1]; b2 = yrow[f+2]; b3 = yrow[f+3]; }
            else       { b0 = nb1[f];  b1 = nb1[f+1];  b2 = nb1[f+2];  b3 = nb1[f+3]; }
#pragma unroll
            for (int mf = 0; mf < 2; ++mf) {
                float vv[4] = {acc[j][mf][0] + b0, acc[j][mf][1] + b1,
                               acc[j][mf][2] + b2, acc[j][mf][3] + b3};
                bf16x4 pk;
#pragma unroll
                for (int r = 0; r < 4; ++r) {
                    float v = isatt ? fmaxf(vv[r], 0.f) : gelu_f(vv[r]);
                    pk[r] = (__bf16)v;
                }
                *reinterpret_cast<bf16x4*>(Y + (mf * 16 + mrow) * 136 + f) = pk;
            }
        }
    }
    __syncthreads();   // b1b

    // ---- P2: combined layer-2 (K=128): waves 0/1 att2 (Y1), waves 2/3 node2 (Y2) ----
#pragma unroll
    for (int j = 0; j < 4; ++j) { acc[j][0] = (f32x4){0.f,0.f,0.f,0.f}; acc[j][1] = (f32x4){0.f,0.f,0.f,0.f}; }
    {
        const __bf16* Yb = U + ((wv < 2) ? 0 : 4352);
        const __bf16* b0p = Yb + mrow * 136;
        const __bf16* b1p = Yb + (16 + mrow) * 136;
#pragma unroll
        for (int kt = 0; kt < 4; ++kt) {
            const int kb = kt * 32 + kg * 8;
            bf16x8 b0 = *reinterpret_cast<const bf16x8*>(b0p + kb);
            bf16x8 b1 = *reinterpret_cast<const bf16x8*>(b1p + kb);
#pragma unroll
            for (int j = 0; j < 4; ++j) {
                bf16x8 a = *reinterpret_cast<const bf16x8*>(wp + OFF_CW2 + (size_t)((kt * 16 + wv * 4 + j) * 64 + lane) * 8);
                acc[j][0] = __builtin_amdgcn_mfma_f32_16x16x32_bf16(a, b0, acc[j][0], 0, 0, 0);
                acc[j][1] = __builtin_amdgcn_mfma_f32_16x16x32_bf16(a, b1, acc[j][1], 0, 0, 0);
            }
        }
    }

    // waves 0/1: relu + fused logit layer (registers + sLP only) before b2a
    if (wv < 2) {
        float lp[2][4];
        lp[0][0]=lp[0][1]=lp[0][2]=lp[0][3]=0.f;
        lp[1][0]=lp[1][1]=lp[1][2]=lp[1][3]=0.f;
#pragma unroll
        for (int j = 0; j < 4; ++j) {
            const int f = (wv & 1) * 64 + j * 16 + kg * 4;
            float b0 = ab2[f], b1 = ab2[f+1], b2 = ab2[f+2], b3 = ab2[f+3];
            float4 w3v[4];
#pragma unroll
            for (int r = 0; r < 4; ++r)
                w3v[r] = *reinterpret_cast<const float4*>(aw3 + (f + r) * 4);
#pragma unroll
            for (int mf = 0; mf < 2; ++mf) {
                float vv[4] = {acc[j][mf][0] + b0, acc[j][mf][1] + b1,
                               acc[j][mf][2] + b2, acc[j][mf][3] + b3};
#pragma unroll
                for (int r = 0; r < 4; ++r) {
                    float v = fmaxf(vv[r], 0.f);
                    lp[mf][0] += v * w3v[r].x;
                    lp[mf][1] += v * w3v[r].y;
                    lp[mf][2] += v * w3v[r].z;
                    lp[mf][3] += v * w3v[r].w;
                }
            }
        }
#pragma unroll
        for (int mf = 0; mf < 2; ++mf)
#pragma unroll
            for (int hh = 0; hh < 4; ++hh) {
                lp[mf][hh] += __shfl_xor(lp[mf][hh], 16);
                lp[mf][hh] += __shfl_xor(lp[mf][hh], 32);
            }
        if (kg == 0) {
#pragma unroll
            for (int mf = 0; mf < 2; ++mf) {
                float4 o = make_float4(lp[mf][0], lp[mf][1], lp[mf][2], lp[mf][3]);
                *reinterpret_cast<float4*>(&sLP[wv][mf * 16 + mrow][0]) = o;
            }
        }
    }
    __syncthreads();   // b2a: Y1 reads done; waves 2/3 may overwrite U[0:4352]

    // waves 2/3: gelu(node2) -> N2 = U[0:4352]
    if (wv >= 2) {
#pragma unroll
        for (int j = 0; j < 4; ++j) {
            const int f = (wv & 1) * 64 + j * 16 + kg * 4;
            float b0 = nb2[f], b1 = nb2[f+1], b2 = nb2[f+2], b3 = nb2[f+3];
#pragma unroll
            for (int mf = 0; mf < 2; ++mf) {
                float vv[4] = {acc[j][mf][0] + b0, acc[j][mf][1] + b1,
                               acc[j][mf][2] + b2, acc[j][mf][3] + b3};
                bf16x4 pk;
#pragma unroll
                for (int r = 0; r < 4; ++r) pk[r] = (__bf16)gelu_f(vv[r]);
                *reinterpret_cast<bf16x4*>(U + (mf * 16 + mrow) * 136 + f) = pk;
            }
        }
    }
    __syncthreads();   // b2b: N2 ready

    // ---- P3: node layer 3 (K=128) over N2; softmax on wave 0 lanes<32 ----
    f32x4 a2[2][2];
    a2[0][0]=(f32x4){0.f,0.f,0.f,0.f}; a2[0][1]=(f32x4){0.f,0.f,0.f,0.f};
    a2[1][0]=(f32x4){0.f,0.f,0.f,0.f}; a2[1][1]=(f32x4){0.f,0.f,0.f,0.f};
    {
        const __bf16* b0p = U + mrow * 136;
        const __bf16* b1p = U + (16 + mrow) * 136;
#pragma unroll
        for (int kt = 0; kt < 4; ++kt) {
            const int kb = kt * 32 + kg * 8;
            bf16x8 b0 = *reinterpret_cast<const bf16x8*>(b0p + kb);
            bf16x8 b1 = *reinterpret_cast<const bf16x8*>(b1p + kb);
#pragma unroll
            for (int j = 0; j < 2; ++j) {
                bf16x8 a = *reinterpret_cast<const bf16x8*>(wp + OFF_NW3 + (size_t)((kt * 8 + wv * 2 + j) * 64 + lane) * 8);
                a2[j][0] = __builtin_amdgcn_mfma_f32_16x16x32_bf16(a, b0, a2[j][0], 0, 0, 0);
                a2[j][1] = __builtin_amdgcn_mfma_f32_16x16x32_bf16(a, b1, a2[j][1], 0, 0, 0);
            }
        }
    }
    if (wv == 0 && lane < 32) {
        const float s = 0.17677669529f;   // 1/sqrt(32)
        float4 lg;
        if (lane < KNEI) {
            float4 p0 = *reinterpret_cast<float4*>(&sLP[0][lane][0]);
            float4 p1 = *reinterpret_cast<float4*>(&sLP[1][lane][0]);
            lg = make_float4((p0.x + p1.x + ab3[0]) * s, (p0.y + p1.y + ab3[1]) * s,
                             (p0.z + p1.z + ab3[2]) * s, (p0.w + p1.w + ab3[3]) * s);
        } else lg = make_float4(-1e30f, -1e30f, -1e30f, -1e30f);
        float4 mx = lg;
#pragma unroll
        for (int msk = 1; msk <= 16; msk <<= 1) {
            mx.x = fmaxf(mx.x, __shfl_xor(mx.x, msk));
            mx.y = fmaxf(mx.y, __shfl_xor(mx.y, msk));
            mx.z = fmaxf(mx.z, __shfl_xor(mx.z, msk));
            mx.w = fmaxf(mx.w, __shfl_xor(mx.w, msk));
        }
        float4 ex = make_float4(__expf(lg.x - mx.x), __expf(lg.y - mx.y),
                                __expf(lg.z - mx.z), __expf(lg.w - mx.w));
        float4 sm = ex;
#pragma unroll
        for (int msk = 1; msk <= 16; msk <<= 1) {
            sm.x += __shfl_xor(sm.x, msk);
            sm.y += __shfl_xor(sm.y, msk);
            sm.z += __shfl_xor(sm.z, msk);
            sm.w += __shfl_xor(sm.w, msk);
        }
        float4 w = make_float4(ex.x / sm.x, ex.y / sm.y, ex.z / sm.z, ex.w / sm.w);
        *reinterpret_cast<float4*>(&sW[lane][0]) = w;   // rows 30/31 -> 0
    }
    __syncthreads();   // b3: sW visible

    // ---- P4: fused aggregation epilogue: pre[node] = sum_m w[m]*(V + nb3) ----
    {
        float wgt0 = sW[mrow][wv];
        float wgt1 = sW[16 + mrow][wv];
        float part[2][4];
#pragma unroll
        for (int j = 0; j < 2; ++j)
#pragma unroll
            for (int r = 0; r < 4; ++r)
                part[j][r] = wgt0 * a2[j][0][r] + wgt1 * a2[j][1][r];
#pragma unroll
        for (int msk = 1; msk <= 8; msk <<= 1)
#pragma unroll
            for (int j = 0; j < 2; ++j)
#pragma unroll
                for (int r = 0; r < 4; ++r)
                    part[j][r] += __shfl_xor(part[j][r], msk);
        if (mrow == 0) {
#pragma unroll
            for (int j = 0; j < 2; ++j) {
                const int nb = wv * 32 + j * 16 + kg * 4;
                float4 o = make_float4(part[j][0] + nb3[nb],     part[j][1] + nb3[nb + 1],
                                       part[j][2] + nb3[nb + 2], part[j][3] + nb3[nb + 3]);
                *reinterpret_cast<float4*>(pre_out + (long)node * DIM + nb) = o;
            }
        }
    }
}

extern "C" void kernel_launch(void* const* d_in, const int* in_sizes, int n_in,
                              void* d_out, int out_size, void* d_ws, size_t ws_size,
                              hipStream_t stream) {
    const float* h   = (const float*)d_in[0];
    const float* e   = (const float*)d_in[1];
    const int*   ei  = (const int*)d_in[2];
    const float* aw1 = (const float*)d_in[3];
    const float* ab1 = (const float*)d_in[4];
    const float* aw2 = (const float*)d_in[5];
    const float* ab2 = (const float*)d_in[6];
    const float* aw3 = (const float*)d_in[7];
    const float* ab3 = (const float*)d_in[8];
    const float* nw1 = (const float*)d_in[9];
    const float* nb1 = (const float*)d_in[10];
    const float* nw2 = (const float*)d_in[11];
    const float* nb2 = (const float*)d_in[12];
    const float* nw3 = (const float*)d_in[13];
    const float* nb3 = (const float*)d_in[14];
    const float* thw = (const float*)d_in[15];
    float* out = (float*)d_out;
    __bf16* wp = (__bf16*)d_ws;
    float* yhi = (float*)((char*)d_ws + YHI_BYTE_OFF);

    // all-weight repack (f32 -> bf16 MFMA-fragment order), one launch
    repack_all<<<TOT_TILES * 2, 256, 0, stream>>>(aw1, aw2, nw1, nw2, nw3, thw, wp);

    const int nblk = (N_NODES + 63) / 64;
    // yhi = h @ att_w1[0:128,:] + ab1   (hi part of att layer 1, per node)
    mm128<<<nblk, 512, 0, stream>>>(h, yhi, wp + OFF_HI, ab1);

    gnn_fused<<<N_NODES, 256, 0, stream>>>(h, e, ei, yhi, ab2, aw3, ab3,
                                           nb1, nb2, nb3, wp, out);
    // out = pre @ to_h_w (in-place)
    mm128<<<nblk, 512, 0, stream>>>(out, out, wp + OFF_TH, nullptr);
}

// Round 7
// 199.913 us; speedup vs baseline: 1.0573x; 1.0573x over previous
//
#include <hip/hip_runtime.h>
#include <hip/hip_bf16.h>

#define N_NODES 10000
#define KNEI    30
#define DIM     128
#define EDGES   (N_NODES * KNEI)

typedef __attribute__((ext_vector_type(4))) float  f32x4;
typedef __attribute__((ext_vector_type(8))) __bf16 bf16x8;
typedef __attribute__((ext_vector_type(4))) __bf16 bf16x4;

// packed bf16 weight offsets in d_ws (element units)
// CW1: K=256, N=256 combined [att_w1(e|hj part) | node_w1]   tiles: kt*16+nt
// CW2: K=128, N=256 combined [att_w2 | node_w2]              tiles: kt*16+nt
// NW3/HI/TH: K=128, N=128                                    tiles: kt*8+nt
#define OFF_CW1 0
#define OFF_CW2 65536
#define OFF_NW3 98304
#define OFF_HI  114688
#define OFF_TH  131072
#define TOT_TILES 288
#define YHI_BYTE_OFF (300 * 1024)   // f32 yhi[N][128] after weights

// Pack all weights (f32) into MFMA A-fragment order, bf16, one launch.
// Within a 512-elem tile: lane holds n = nt*16+(lane&15), k = kt*32+(lane>>4)*8+i.
__global__ __launch_bounds__(256) void repack_all(
    const float* __restrict__ aw1, const float* __restrict__ aw2,
    const float* __restrict__ nw1, const float* __restrict__ nw2,
    const float* __restrict__ nw3, const float* __restrict__ thw,
    __bf16* __restrict__ dst) {
    int t = blockIdx.x * 256 + threadIdx.x;
    if (t >= TOT_TILES * 512) return;
    int tile = t >> 9;
    int i    = t & 7;
    int lane = (t >> 3) & 63;
    int krow = ((lane >> 4) << 3) + i;   // 0..31
    int ncol = lane & 15;
    float v;
    if (tile < 128) {                    // CW1
        int kt = tile >> 4, nt = tile & 15;
        int k = kt * 32 + krow, n = nt * 16 + ncol;
        v = (n < 128) ? aw1[(128 + k) * 128 + n] : nw1[k * 128 + (n - 128)];
    } else if (tile < 192) {             // CW2
        int lt = tile - 128;
        int kt = lt >> 4, nt = lt & 15;
        int k = kt * 32 + krow, n = nt * 16 + ncol;
        v = (n < 128) ? aw2[k * 128 + n] : nw2[k * 128 + (n - 128)];
    } else {                             // NW3 / HI / TH (32 tiles each)
        int lt = tile & 31;
        int kt = lt >> 3, nt = lt & 7;
        int k = kt * 32 + krow, n = nt * 16 + ncol;
        const float* s = (tile < 224) ? nw3 : (tile < 256) ? aw1 : thw;
        v = s[k * 128 + n];
    }
    dst[t] = (__bf16)v;
}

// fast gelu (tanh form; abs err ~2e-4, << bf16 noise)
__device__ __forceinline__ float gelu_f(float x) {
    float u = 0.7978845608f * (x + 0.044715f * x * x * x);
    float t = 1.f - 2.f / (__expf(2.f * u) + 1.f);
    return 0.5f * x * (1.f + t);
}

__device__ __forceinline__ bf16x4 cvt4(float4 v) {
    bf16x4 r;
    r[0] = (__bf16)v.x; r[1] = (__bf16)v.y; r[2] = (__bf16)v.z; r[3] = (__bf16)v.w;
    return r;
}

// ---- generic 128->128 row GEMM (64 rows/block, 8 waves): out = in @ Wfrag (+bias) ----
__global__ __launch_bounds__(512) void mm128(const float* __restrict__ in,
                                             float* __restrict__ outp,
                                             const __bf16* __restrict__ wfrag,
                                             const float* __restrict__ bias) {
    __shared__ __bf16 sP[64 * 136];
    const int tid  = threadIdx.x;
    const int wv   = tid >> 6;
    const int lane = tid & 63;
    const int mrow = lane & 15;
    const int kgrp = lane >> 4;
    const int base = blockIdx.x * 64;

#pragma unroll
    for (int c = 0; c < 4; ++c) {
        int idx = c * 512 + tid;
        int m  = idx >> 5;
        int jv = idx & 31;
        int row = base + m;
        float4 v = make_float4(0.f, 0.f, 0.f, 0.f);
        if (row < N_NODES) v = *reinterpret_cast<const float4*>(in + (long)row * DIM + jv * 4);
        *reinterpret_cast<bf16x4*>(&sP[m * 136 + jv * 4]) = cvt4(v);
    }
    __syncthreads();

    f32x4 acc[4];
#pragma unroll
    for (int mf = 0; mf < 4; ++mf) acc[mf] = (f32x4){0.f, 0.f, 0.f, 0.f};
#pragma unroll
    for (int kt = 0; kt < 4; ++kt) {
        bf16x8 a = *reinterpret_cast<const bf16x8*>(wfrag + ((kt * 8 + wv) * 64 + lane) * 8);
        const int kb = kt * 32 + kgrp * 8;
#pragma unroll
        for (int mf = 0; mf < 4; ++mf) {
            bf16x8 b = *reinterpret_cast<const bf16x8*>(sP + (mf * 16 + mrow) * 136 + kb);
            acc[mf] = __builtin_amdgcn_mfma_f32_16x16x32_bf16(a, b, acc[mf], 0, 0, 0);
        }
    }
    const int nb = wv * 16 + kgrp * 4;
    float b0 = 0.f, b1 = 0.f, b2 = 0.f, b3 = 0.f;
    if (bias) { b0 = bias[nb]; b1 = bias[nb + 1]; b2 = bias[nb + 2]; b3 = bias[nb + 3]; }
#pragma unroll
    for (int mf = 0; mf < 4; ++mf) {
        int row = base + mf * 16 + mrow;
        if (row < N_NODES) {
            float4 o = make_float4(acc[mf][0] + b0, acc[mf][1] + b1,
                                   acc[mf][2] + b2, acc[mf][3] + b3);
            *reinterpret_cast<float4*>(outp + (long)row * DIM + nb) = o;
        }
    }
}

// ---- fused kernel: one block = 1 node (30 edges padded to 32 rows), 4 waves ----
// Layer-1 and layer-2 of both MLPs run as COMBINED 256-output GEMMs (shared or
// wave-split inputs). LDS: union buffer U = S[32][264] then Y1@0 | Y2@4352.
// NOTE: launch_bounds min-waves kept at 4 — 6+ forces VGPR<needed and spills
// ~75 MB of scratch per dispatch (measured r3, r6). Do not raise.
__global__ __launch_bounds__(256, 4) void gnn_fused(
    const float* __restrict__ h, const float* __restrict__ e, const int* __restrict__ eidx,
    const float* __restrict__ yhi,
    const float* __restrict__ ab2, const float* __restrict__ aw3, const float* __restrict__ ab3,
    const float* __restrict__ nb1, const float* __restrict__ nb2, const float* __restrict__ nb3,
    const __bf16* __restrict__ wp, float* __restrict__ pre_out) {

    __shared__ __bf16 U[8704];          // S: stride 264 (8448 used) ; later Y1@0, Y2@4352 (stride 136)
    __shared__ float  sLP[2][32][4];    // logit partials (wave-half 0/1)
    __shared__ float  sW[32][4];        // softmax weights (rows 30/31 = 0)

    const int tid  = threadIdx.x;
    const int wv   = tid >> 6;
    const int lane = tid & 63;
    const int mrow = lane & 15;
    const int kg   = lane >> 4;
    const int node = blockIdx.x;
    const long ebase = (long)node * KNEI;

    // ---- P0: stage e|hj (f32 -> bf16), pad rows 30/31 = 0 ----
#pragma unroll
    for (int c = 0; c < 4; ++c) {
        int idx = c * 256 + tid;
        int m  = idx >> 5;   // row 0..31
        int jv = idx & 31;   // float4 col
        float4 ev = make_float4(0.f, 0.f, 0.f, 0.f), hjv = ev;
        if (m < KNEI) {
            long ge = ebase + m;
            ev  = *reinterpret_cast<const float4*>(e + ge * DIM + jv * 4);
            int dstn = eidx[EDGES + ge];
            hjv = *reinterpret_cast<const float4*>(h + (long)dstn * DIM + jv * 4);
        }
        *reinterpret_cast<bf16x4*>(&U[m * 264 + jv * 4])       = cvt4(ev);
        *reinterpret_cast<bf16x4*>(&U[m * 264 + 128 + jv * 4]) = cvt4(hjv);
    }
    __syncthreads();   // b0

    f32x4 acc[4][2];
#pragma unroll
    for (int j = 0; j < 4; ++j) { acc[j][0] = (f32x4){0.f,0.f,0.f,0.f}; acc[j][1] = (f32x4){0.f,0.f,0.f,0.f}; }

    // ---- P1: combined layer-1 (K=256): [att1 | node1] over shared [e|hj] ----
    {
        const __bf16* b0p = U + mrow * 264;
        const __bf16* b1p = U + (16 + mrow) * 264;
#pragma unroll
        for (int kt = 0; kt < 8; ++kt) {
            const int kb = kt * 32 + kg * 8;
            bf16x8 b0 = *reinterpret_cast<const bf16x8*>(b0p + kb);
            bf16x8 b1 = *reinterpret_cast<const bf16x8*>(b1p + kb);
#pragma unroll
            for (int j = 0; j < 4; ++j) {
                bf16x8 a = *reinterpret_cast<const bf16x8*>(wp + OFF_CW1 + (size_t)((kt * 16 + wv * 4 + j) * 64 + lane) * 8);
                acc[j][0] = __builtin_amdgcn_mfma_f32_16x16x32_bf16(a, b0, acc[j][0], 0, 0, 0);
                acc[j][1] = __builtin_amdgcn_mfma_f32_16x16x32_bf16(a, b1, acc[j][1], 0, 0, 0);
            }
        }
    }
    __syncthreads();   // b1a: all reads of S done; U re-carved as Y1|Y2

    // ---- epilogue 1: waves 0/1 -> relu(acc + yhi) -> Y1 ; waves 2/3 -> gelu(acc + nb1) -> Y2 ----
    {
        const bool isatt = (wv < 2);
        __bf16* Y = U + (isatt ? 0 : 4352);
        const float* yrow = yhi + (long)node * DIM;
#pragma unroll
        for (int j = 0; j < 4; ++j) {
            const int f = (wv & 1) * 64 + j * 16 + kg * 4;
            float b0, b1, b2, b3;
            if (isatt) { b0 = yrow[f]; b1 = yrow[f+1]; b2 = yrow[f+2]; b3 = yrow[f+3]; }
            else       { b0 = nb1[f];  b1 = nb1[f+1];  b2 = nb1[f+2];  b3 = nb1[f+3]; }
#pragma unroll
            for (int mf = 0; mf < 2; ++mf) {
                float vv[4] = {acc[j][mf][0] + b0, acc[j][mf][1] + b1,
                               acc[j][mf][2] + b2, acc[j][mf][3] + b3};
                bf16x4 pk;
#pragma unroll
                for (int r = 0; r < 4; ++r) {
                    float v = isatt ? fmaxf(vv[r], 0.f) : gelu_f(vv[r]);
                    pk[r] = (__bf16)v;
                }
                *reinterpret_cast<bf16x4*>(Y + (mf * 16 + mrow) * 136 + f) = pk;
            }
        }
    }
    __syncthreads();   // b1b

    // ---- P2: combined layer-2 (K=128): waves 0/1 att2 (Y1), waves 2/3 node2 (Y2) ----
#pragma unroll
    for (int j = 0; j < 4; ++j) { acc[j][0] = (f32x4){0.f,0.f,0.f,0.f}; acc[j][1] = (f32x4){0.f,0.f,0.f,0.f}; }
    {
        const __bf16* Yb = U + ((wv < 2) ? 0 : 4352);
        const __bf16* b0p = Yb + mrow * 136;
        const __bf16* b1p = Yb + (16 + mrow) * 136;
#pragma unroll
        for (int kt = 0; kt < 4; ++kt) {
            const int kb = kt * 32 + kg * 8;
            bf16x8 b0 = *reinterpret_cast<const bf16x8*>(b0p + kb);
            bf16x8 b1 = *reinterpret_cast<const bf16x8*>(b1p + kb);
#pragma unroll
            for (int j = 0; j < 4; ++j) {
                bf16x8 a = *reinterpret_cast<const bf16x8*>(wp + OFF_CW2 + (size_t)((kt * 16 + wv * 4 + j) * 64 + lane) * 8);
                acc[j][0] = __builtin_amdgcn_mfma_f32_16x16x32_bf16(a, b0, acc[j][0], 0, 0, 0);
                acc[j][1] = __builtin_amdgcn_mfma_f32_16x16x32_bf16(a, b1, acc[j][1], 0, 0, 0);
            }
        }
    }

    // waves 0/1: relu + fused logit layer (registers + sLP only) before b2a
    if (wv < 2) {
        float lp[2][4];
        lp[0][0]=lp[0][1]=lp[0][2]=lp[0][3]=0.f;
        lp[1][0]=lp[1][1]=lp[1][2]=lp[1][3]=0.f;
#pragma unroll
        for (int j = 0; j < 4; ++j) {
            const int f = (wv & 1) * 64 + j * 16 + kg * 4;
            float b0 = ab2[f], b1 = ab2[f+1], b2 = ab2[f+2], b3 = ab2[f+3];
            float4 w3v[4];
#pragma unroll
            for (int r = 0; r < 4; ++r)
                w3v[r] = *reinterpret_cast<const float4*>(aw3 + (f + r) * 4);
#pragma unroll
            for (int mf = 0; mf < 2; ++mf) {
                float vv[4] = {acc[j][mf][0] + b0, acc[j][mf][1] + b1,
                               acc[j][mf][2] + b2, acc[j][mf][3] + b3};
#pragma unroll
                for (int r = 0; r < 4; ++r) {
                    float v = fmaxf(vv[r], 0.f);
                    lp[mf][0] += v * w3v[r].x;
                    lp[mf][1] += v * w3v[r].y;
                    lp[mf][2] += v * w3v[r].z;
                    lp[mf][3] += v * w3v[r].w;
                }
            }
        }
#pragma unroll
        for (int mf = 0; mf < 2; ++mf)
#pragma unroll
            for (int hh = 0; hh < 4; ++hh) {
                lp[mf][hh] += __shfl_xor(lp[mf][hh], 16);
                lp[mf][hh] += __shfl_xor(lp[mf][hh], 32);
            }
        if (kg == 0) {
#pragma unroll
            for (int mf = 0; mf < 2; ++mf) {
                float4 o = make_float4(lp[mf][0], lp[mf][1], lp[mf][2], lp[mf][3]);
                *reinterpret_cast<float4*>(&sLP[wv][mf * 16 + mrow][0]) = o;
            }
        }
    }
    __syncthreads();   // b2a: Y1 reads done; waves 2/3 may overwrite U[0:4352]

    // waves 2/3: gelu(node2) -> N2 = U[0:4352]
    if (wv >= 2) {
#pragma unroll
        for (int j = 0; j < 4; ++j) {
            const int f = (wv & 1) * 64 + j * 16 + kg * 4;
            float b0 = nb2[f], b1 = nb2[f+1], b2 = nb2[f+2], b3 = nb2[f+3];
#pragma unroll
            for (int mf = 0; mf < 2; ++mf) {
                float vv[4] = {acc[j][mf][0] + b0, acc[j][mf][1] + b1,
                               acc[j][mf][2] + b2, acc[j][mf][3] + b3};
                bf16x4 pk;
#pragma unroll
                for (int r = 0; r < 4; ++r) pk[r] = (__bf16)gelu_f(vv[r]);
                *reinterpret_cast<bf16x4*>(U + (mf * 16 + mrow) * 136 + f) = pk;
            }
        }
    }
    __syncthreads();   // b2b: N2 ready

    // ---- P3: node layer 3 (K=128) over N2; softmax on wave 0 lanes<32 ----
    f32x4 a2[2][2];
    a2[0][0]=(f32x4){0.f,0.f,0.f,0.f}; a2[0][1]=(f32x4){0.f,0.f,0.f,0.f};
    a2[1][0]=(f32x4){0.f,0.f,0.f,0.f}; a2[1][1]=(f32x4){0.f,0.f,0.f,0.f};
    {
        const __bf16* b0p = U + mrow * 136;
        const __bf16* b1p = U + (16 + mrow) * 136;
#pragma unroll
        for (int kt = 0; kt < 4; ++kt) {
            const int kb = kt * 32 + kg * 8;
            bf16x8 b0 = *reinterpret_cast<const bf16x8*>(b0p + kb);
            bf16x8 b1 = *reinterpret_cast<const bf16x8*>(b1p + kb);
#pragma unroll
            for (int j = 0; j < 2; ++j) {
                bf16x8 a = *reinterpret_cast<const bf16x8*>(wp + OFF_NW3 + (size_t)((kt * 8 + wv * 2 + j) * 64 + lane) * 8);
                a2[j][0] = __builtin_amdgcn_mfma_f32_16x16x32_bf16(a, b0, a2[j][0], 0, 0, 0);
                a2[j][1] = __builtin_amdgcn_mfma_f32_16x16x32_bf16(a, b1, a2[j][1], 0, 0, 0);
            }
        }
    }
    if (wv == 0 && lane < 32) {
        const float s = 0.17677669529f;   // 1/sqrt(32)
        float4 lg;
        if (lane < KNEI) {
            float4 p0 = *reinterpret_cast<float4*>(&sLP[0][lane][0]);
            float4 p1 = *reinterpret_cast<float4*>(&sLP[1][lane][0]);
            lg = make_float4((p0.x + p1.x + ab3[0]) * s, (p0.y + p1.y + ab3[1]) * s,
                             (p0.z + p1.z + ab3[2]) * s, (p0.w + p1.w + ab3[3]) * s);
        } else lg = make_float4(-1e30f, -1e30f, -1e30f, -1e30f);
        float4 mx = lg;
#pragma unroll
        for (int msk = 1; msk <= 16; msk <<= 1) {
            mx.x = fmaxf(mx.x, __shfl_xor(mx.x, msk));
            mx.y = fmaxf(mx.y, __shfl_xor(mx.y, msk));
            mx.z = fmaxf(mx.z, __shfl_xor(mx.z, msk));
            mx.w = fmaxf(mx.w, __shfl_xor(mx.w, msk));
        }
        float4 ex = make_float4(__expf(lg.x - mx.x), __expf(lg.y - mx.y),
                                __expf(lg.z - mx.z), __expf(lg.w - mx.w));
        float4 sm = ex;
#pragma unroll
        for (int msk = 1; msk <= 16; msk <<= 1) {
            sm.x += __shfl_xor(sm.x, msk);
            sm.y += __shfl_xor(sm.y, msk);
            sm.z += __shfl_xor(sm.z, msk);
            sm.w += __shfl_xor(sm.w, msk);
        }
        float4 w = make_float4(ex.x / sm.x, ex.y / sm.y, ex.z / sm.z, ex.w / sm.w);
        *reinterpret_cast<float4*>(&sW[lane][0]) = w;   // rows 30/31 -> 0
    }
    __syncthreads();   // b3: sW visible

    // ---- P4: fused aggregation epilogue: pre[node] = sum_m w[m]*(V + nb3) ----
    {
        float wgt0 = sW[mrow][wv];
        float wgt1 = sW[16 + mrow][wv];
        float part[2][4];
#pragma unroll
        for (int j = 0; j < 2; ++j)
#pragma unroll
            for (int r = 0; r < 4; ++r)
                part[j][r] = wgt0 * a2[j][0][r] + wgt1 * a2[j][1][r];
#pragma unroll
        for (int msk = 1; msk <= 8; msk <<= 1)
#pragma unroll
            for (int j = 0; j < 2; ++j)
#pragma unroll
                for (int r = 0; r < 4; ++r)
                    part[j][r] += __shfl_xor(part[j][r], msk);
        if (mrow == 0) {
#pragma unroll
            for (int j = 0; j < 2; ++j) {
                const int nb = wv * 32 + j * 16 + kg * 4;
                float4 o = make_float4(part[j][0] + nb3[nb],     part[j][1] + nb3[nb + 1],
                                       part[j][2] + nb3[nb + 2], part[j][3] + nb3[nb + 3]);
                *reinterpret_cast<float4*>(pre_out + (long)node * DIM + nb) = o;
            }
        }
    }
}

extern "C" void kernel_launch(void* const* d_in, const int* in_sizes, int n_in,
                              void* d_out, int out_size, void* d_ws, size_t ws_size,
                              hipStream_t stream) {
    const float* h   = (const float*)d_in[0];
    const float* e   = (const float*)d_in[1];
    const int*   ei  = (const int*)d_in[2];
    const float* aw1 = (const float*)d_in[3];
    const float* ab1 = (const float*)d_in[4];
    const float* aw2 = (const float*)d_in[5];
    const float* ab2 = (const float*)d_in[6];
    const float* aw3 = (const float*)d_in[7];
    const float* ab3 = (const float*)d_in[8];
    const float* nw1 = (const float*)d_in[9];
    const float* nb1 = (const float*)d_in[10];
    const float* nw2 = (const float*)d_in[11];
    const float* nb2 = (const float*)d_in[12];
    const float* nw3 = (const float*)d_in[13];
    const float* nb3 = (const float*)d_in[14];
    const float* thw = (const float*)d_in[15];
    float* out = (float*)d_out;
    __bf16* wp = (__bf16*)d_ws;
    float* yhi = (float*)((char*)d_ws + YHI_BYTE_OFF);

    // all-weight repack (f32 -> bf16 MFMA-fragment order), one launch
    repack_all<<<TOT_TILES * 2, 256, 0, stream>>>(aw1, aw2, nw1, nw2, nw3, thw, wp);

    const int nblk = (N_NODES + 63) / 64;
    // yhi = h @ att_w1[0:128,:] + ab1   (hi part of att layer 1, per node)
    mm128<<<nblk, 512, 0, stream>>>(h, yhi, wp + OFF_HI, ab1);

    gnn_fused<<<N_NODES, 256, 0, stream>>>(h, e, ei, yhi, ab2, aw3, ab3,
                                           nb1, nb2, nb3, wp, out);
    // out = pre @ to_h_w (in-place)
    mm128<<<nblk, 512, 0, stream>>>(out, out, wp + OFF_TH, nullptr);
}